// Round 4
// baseline (328.040 us; speedup 1.0000x reference)
//
#include <hip/hip_runtime.h>

typedef __attribute__((ext_vector_type(8))) short bf16x8;
typedef __attribute__((ext_vector_type(4))) float f32x4;
typedef __attribute__((ext_vector_type(16))) float f32x16;

__device__ __forceinline__ unsigned short f2bf(float f) {  // RNE
    union { float f; unsigned u; } v; v.f = f;
    return (unsigned short)((v.u + 0x7FFFu + ((v.u >> 16) & 1u)) >> 16);
}
// packed round-half-up (hot path; differs from RNE only at exact ties)
__device__ __forceinline__ unsigned f2bf2_fast(float a, float b) {
    union { float f; unsigned u; } va, vb; va.f = a; vb.f = b;
    return ((va.u + 0x8000u) >> 16) | ((vb.u + 0x8000u) & 0xFFFF0000u);
}

__device__ __forceinline__ void async16(unsigned short* lds, const unsigned short* gsrc) {
    __builtin_amdgcn_global_load_lds(
        (const __attribute__((address_space(1))) void*)gsrc,
        (__attribute__((address_space(3))) void*)lds, 16, 0, 0);
}

// ---------------- Kernel 0: weight transpose + bf16 cast ----------------
__global__ __launch_bounds__(256) void k_wt(const float* __restrict__ kf,
                                            const float* __restrict__ kg,
                                            const float* __restrict__ kh,
                                            unsigned short* __restrict__ wt) {
    int n = blockIdx.x, t = threadIdx.x;
    const float* src; int stride, col;
    if (n < 32)      { src = kf; stride = 32;  col = n; }
    else if (n < 64) { src = kg; stride = 32;  col = n - 32; }
    else             { src = kh; stride = 256; col = n - 64; }
    wt[n * 256 + t] = f2bf(src[t * stride + col]);
}

// ---------------- Kernel 1: fused projections (fg + h) ------------------
// blocks [0,256): f,g.  blocks [256,512): hT — each block does ALL 4
// channel-tiles for its 64 rows (x staged once, 4x less x traffic).
__global__ __launch_bounds__(256) void k_proj(const float* __restrict__ x,
                                              const unsigned short* __restrict__ wt,
                                              unsigned short* __restrict__ f,
                                              unsigned short* __restrict__ g,
                                              unsigned short* __restrict__ hT) {
    __shared__ unsigned short s0[64][136];
    __shared__ unsigned short s1[64][136];
    int t = threadIdx.x;
    int w = t >> 6, lane = t & 63, q = lane >> 4, n15 = lane & 15;

    if (blockIdx.x < 256) {
        int rb = blockIdx.x;
        f32x4 acc[4];
#pragma unroll
        for (int i = 0; i < 4; ++i) acc[i] = (f32x4){0.f, 0.f, 0.f, 0.f};
        for (int kh2 = 0; kh2 < 2; ++kh2) {
            __syncthreads();
#pragma unroll
            for (int i = 0; i < 8; ++i) {
                int lin = i * 256 + t, row = lin >> 5, c4 = lin & 31;
                float4 v = *(const float4*)&x[(rb * 64 + row) * 256 + kh2 * 128 + c4 * 4];
                ushort4 o; o.x = f2bf(v.x); o.y = f2bf(v.y); o.z = f2bf(v.z); o.w = f2bf(v.w);
                *(ushort4*)&s0[row][c4 * 4] = o;
            }
#pragma unroll
            for (int i = 0; i < 4; ++i) {
                int lin = i * 256 + t, row = lin >> 4, s = lin & 15;
                *(uint4*)&s1[row][s * 8] = *(const uint4*)&wt[row * 256 + kh2 * 128 + s * 8];
            }
            __syncthreads();
#pragma unroll
            for (int kk = 0; kk < 4; ++kk) {
                bf16x8 a = *(const bf16x8*)&s0[w * 16 + n15][kk * 32 + q * 8];
#pragma unroll
                for (int nt = 0; nt < 4; ++nt) {
                    bf16x8 bw = *(const bf16x8*)&s1[nt * 16 + n15][kk * 32 + q * 8];
                    acc[nt] = __builtin_amdgcn_mfma_f32_16x16x32_bf16(a, bw, acc[nt], 0, 0, 0);
                }
            }
        }
#pragma unroll
        for (int nt = 0; nt < 4; ++nt)
#pragma unroll
            for (int r = 0; r < 4; ++r) {
                int grow = rb * 64 + w * 16 + q * 4 + r;
                int col = nt * 16 + n15;
                unsigned short v = f2bf(acc[nt][r]);
                if (col < 32) f[grow * 32 + col] = v;
                else          g[grow * 32 + (col - 32)] = v;
            }
    } else {
        int rt = blockIdx.x - 256;
        int b = rt >> 6, nbase = (rt & 63) * 64;
        f32x4 acc[4][4];
#pragma unroll
        for (int c = 0; c < 4; ++c)
#pragma unroll
            for (int i = 0; i < 4; ++i) acc[c][i] = (f32x4){0.f, 0.f, 0.f, 0.f};
        for (int kh2 = 0; kh2 < 2; ++kh2) {
            __syncthreads();
#pragma unroll
            for (int i = 0; i < 8; ++i) {
                int lin = i * 256 + t, row = lin >> 5, c4 = lin & 31;
                float4 v = *(const float4*)&x[(rt * 64 + row) * 256 + kh2 * 128 + c4 * 4];
                ushort4 o; o.x = f2bf(v.x); o.y = f2bf(v.y); o.z = f2bf(v.z); o.w = f2bf(v.w);
                *(ushort4*)&s0[row][c4 * 4] = o;
            }
            for (int ct = 0; ct < 4; ++ct) {
                if (ct) __syncthreads();
#pragma unroll
                for (int i = 0; i < 4; ++i) {
                    int lin = i * 256 + t, row = lin >> 4, s = lin & 15;
                    *(uint4*)&s1[row][s * 8] =
                        *(const uint4*)&wt[(64 + ct * 64 + row) * 256 + kh2 * 128 + s * 8];
                }
                __syncthreads();
#pragma unroll
                for (int kk = 0; kk < 4; ++kk) {
                    bf16x8 a = *(const bf16x8*)&s1[w * 16 + n15][kk * 32 + q * 8];
#pragma unroll
                    for (int nt = 0; nt < 4; ++nt) {
                        bf16x8 bx = *(const bf16x8*)&s0[nt * 16 + n15][kk * 32 + q * 8];
                        acc[ct][nt] = __builtin_amdgcn_mfma_f32_16x16x32_bf16(a, bx, acc[ct][nt], 0, 0, 0);
                    }
                }
            }
        }
#pragma unroll
        for (int ct = 0; ct < 4; ++ct)
#pragma unroll
            for (int nt = 0; nt < 4; ++nt)
#pragma unroll
                for (int r = 0; r < 4; ++r) {
                    int ch = ct * 64 + w * 16 + q * 4 + r;
                    int nloc = nbase + nt * 16 + n15;
                    hT[b * 1048576 + ch * 4096 + nloc] = f2bf(acc[ct][nt][r]);
                }
    }
}

// ---------------- Kernel 2: fused flash attention + residual ------------
// 512 thr = 8 waves: rh = w>>2 (32-row half), cq = w&3 (64-ch quarter).
// 32x32x16 MFMA. S^T = G.F^T so softmax lane owns ONE row (l&31) and the
// exp'd P converts to PV A-layout with in-register shuffles (no LDS trip).
// Single barrier/iter + async double-buffered staging.
__global__ __launch_bounds__(512, 2) void k_attn(const float* __restrict__ x,
                                                 const unsigned short* __restrict__ f,
                                                 const unsigned short* __restrict__ g,
                                                 const unsigned short* __restrict__ hT,
                                                 const float* __restrict__ gamma_p,
                                                 float* __restrict__ out) {
    __shared__ unsigned short gs[2][64][32];   // keys x 32 dims (seg-swizzled)   8 KB
    __shared__ unsigned short hs[2][256][64];  // ch x 64 keys (seg-swizzled)    64 KB
    __shared__ float als[8][32];               // per-wave alpha/rinv bcast       1 KB
    int t = threadIdx.x, bx = blockIdx.x;
    int b = (bx >> 1) & 3;                     // XCD swizzle: one batch per XCD
    int qt = ((bx & 1) << 5) | (bx >> 3);
    int qbase = qt * 64;
    int w = t >> 6, l = t & 63, hi = l >> 5, l31 = l & 31;
    int rh = w >> 2, cq = w & 3;

    // F B-frags: B[n=l31 (row)][k = ks*16 + hi*8 + j]
    const unsigned short* frow = f + (b * 4096 + qbase + rh * 32 + l31) * 32;
    bf16x8 aFB0 = *(const bf16x8*)&frow[hi * 8];
    bf16x8 aFB1 = *(const bf16x8*)&frow[16 + hi * 8];

    // staging source pointers (swizzle baked into source address)
    const unsigned short* hsrc = hT + b * 1048576 + (w * 32 + (l >> 3)) * 4096
                               + ((l & 7) ^ (l >> 3)) * 8;
    const unsigned short* gsrc = g + (b * 4096 + w * 16 + (l >> 2)) * 32
                               + ((l & 3) ^ ((l >> 2) & 3)) * 8;   // waves 0-3 only

    f32x16 o0, o1;
#pragma unroll
    for (int i = 0; i < 16; ++i) { o0[i] = 0.f; o1[i] = 0.f; }
    float m_run = -1e30f, l_run = 0.f;

    // prefetch tile 0
#pragma unroll
    for (int j = 0; j < 4; ++j) async16(&hs[0][w * 32 + j * 8][0], hsrc + j * 8 * 4096);
    if (w < 4) async16(&gs[0][w * 16][0], gsrc);

    const int pg0 = (hi ^ (l31 & 3)) * 8;          // gs phys seg, dim-half 0
    const int pg1 = ((2 + hi) ^ (l31 & 3)) * 8;    // dim-half 1
    const unsigned short* hrow0 = &hs[0][cq * 64 + l31][0];
    const unsigned short* hrow1 = &hs[0][cq * 64 + 32 + l31][0];

    for (int kt = 0; kt < 64; ++kt) {
        int cur = kt & 1, nxt = cur ^ 1;
        __syncthreads();   // drains prefetch(kt); guards buffer reuse

        if (kt + 1 < 64) {
            const unsigned short* hp = hsrc + (kt + 1) * 64;
#pragma unroll
            for (int j = 0; j < 4; ++j)
                async16(&hs[nxt][w * 32 + j * 8][0], hp + j * 8 * 4096);
            if (w < 4) async16(&gs[nxt][w * 16][0], gsrc + (kt + 1) * 2048);
        }

        // ---- S^T = G . F^T : 2 key-tiles x 2 dim-halves ----
        f32x16 s0, s1;
#pragma unroll
        for (int i = 0; i < 16; ++i) { s0[i] = 0.f; s1[i] = 0.f; }
        {
            const unsigned short* g0 = &gs[cur][l31][0];
            const unsigned short* g1 = &gs[cur][32 + l31][0];
            bf16x8 a00 = *(const bf16x8*)&g0[pg0];
            bf16x8 a01 = *(const bf16x8*)&g0[pg1];
            bf16x8 a10 = *(const bf16x8*)&g1[pg0];
            bf16x8 a11 = *(const bf16x8*)&g1[pg1];
            s0 = __builtin_amdgcn_mfma_f32_32x32x16_bf16(a00, aFB0, s0, 0, 0, 0);
            s0 = __builtin_amdgcn_mfma_f32_32x32x16_bf16(a01, aFB1, s0, 0, 0, 0);
            s1 = __builtin_amdgcn_mfma_f32_32x32x16_bf16(a10, aFB0, s1, 0, 0, 0);
            s1 = __builtin_amdgcn_mfma_f32_32x32x16_bf16(a11, aFB1, s1, 0, 0, 0);
        }

        // ---- online softmax: lane owns row l31 (+rh*32); keys split by hi ----
        float mx = s0[0];
#pragma unroll
        for (int i = 1; i < 16; ++i) mx = fmaxf(mx, s0[i]);
#pragma unroll
        for (int i = 0; i < 16; ++i) mx = fmaxf(mx, s1[i]);
        mx = fmaxf(mx, __shfl_xor(mx, 32));
        float mnew = fmaxf(m_run, mx);
        float alpha = __expf(m_run - mnew);
        float psum = 0.f;
#pragma unroll
        for (int i = 0; i < 16; ++i) { s0[i] = __expf(s0[i] - mnew); psum += s0[i]; }
#pragma unroll
        for (int i = 0; i < 16; ++i) { s1[i] = __expf(s1[i] - mnew); psum += s1[i]; }
        psum += __shfl_xor(psum, 32);
        l_run = l_run * alpha + psum;
        m_run = mnew;
        als[w][l31] = alpha;

        // pack P to bf16 pairs: pk[mt][qq] = keys mt*32 + 8qq + 4hi + {0..3}
        // (C/D reg i=4qq+r -> local key r + 8qq + 4hi)
        unsigned pk[2][4][2];
#pragma unroll
        for (int qq = 0; qq < 4; ++qq) {
            pk[0][qq][0] = f2bf2_fast(s0[4 * qq + 0], s0[4 * qq + 1]);
            pk[0][qq][1] = f2bf2_fast(s0[4 * qq + 2], s0[4 * qq + 3]);
            pk[1][qq][0] = f2bf2_fast(s1[4 * qq + 0], s1[4 * qq + 1]);
            pk[1][qq][1] = f2bf2_fast(s1[4 * qq + 2], s1[4 * qq + 3]);
        }

        // rescale O by alpha (broadcast via als: rows 8q+4hi+j)
#pragma unroll
        for (int qq = 0; qq < 4; ++qq) {
            f32x4 al = *(const f32x4*)&als[w][8 * qq + 4 * hi];
#pragma unroll
            for (int j = 0; j < 4; ++j) {
                o0[4 * qq + j] *= al[j];
                o1[4 * qq + j] *= al[j];
            }
        }

        // ---- O += P.H : A-frag needs keys 16k1+8hi+{0..7} on lane hi, i.e.
        // entry qq=2k1+hi from BOTH lane-halves. shfl_xor(32) is an exchange:
        // keep own pk[mt][2k1+hi], SEND pk[mt][2k1+1-hi] (partner's keep idx).
        const unsigned short* h0 = hrow0 + cur * (256 * 64);
        const unsigned short* h1 = hrow1 + cur * (256 * 64);
#pragma unroll
        for (int ks = 0; ks < 4; ++ks) {
            const int mt = ks >> 1, k1 = ks & 1;
            unsigned keep0 = pk[mt][2 * k1 + hi][0];
            unsigned keep1 = pk[mt][2 * k1 + hi][1];
            unsigned send0 = pk[mt][2 * k1 + 1 - hi][0];
            unsigned send1 = pk[mt][2 * k1 + 1 - hi][1];
            unsigned recv0 = (unsigned)__shfl_xor((int)send0, 32);
            unsigned recv1 = (unsigned)__shfl_xor((int)send1, 32);
            union { unsigned u[4]; bf16x8 v; } ap;
            ap.u[0] = hi ? recv0 : keep0;   // keys 16k1+8hi+{0,1} (from h'=0 lane)
            ap.u[1] = hi ? recv1 : keep1;   // keys 16k1+8hi+{2,3}
            ap.u[2] = hi ? keep0 : recv0;   // keys 16k1+8hi+{4,5} (from h'=1 lane)
            ap.u[3] = hi ? keep1 : recv1;   // keys 16k1+8hi+{6,7}
            int ph = ((2 * ks + hi) ^ (l31 & 7)) * 8;
            bf16x8 bH0 = *(const bf16x8*)&h0[ph];
            bf16x8 bH1 = *(const bf16x8*)&h1[ph];
            o0 = __builtin_amdgcn_mfma_f32_32x32x16_bf16(ap.v, bH0, o0, 0, 0, 0);
            o1 = __builtin_amdgcn_mfma_f32_32x32x16_bf16(ap.v, bH1, o1, 0, 0, 0);
        }
    }

    // ---- epilogue: O/l, residual, store ----
    als[w][l31] = 1.0f / l_run;        // same-wave write->read, in order
    float gam = *gamma_p;
#pragma unroll
    for (int qq = 0; qq < 4; ++qq) {
        f32x4 ri = *(const f32x4*)&als[w][8 * qq + 4 * hi];
#pragma unroll
        for (int j = 0; j < 4; ++j) {
            int row = qbase + rh * 32 + 8 * qq + 4 * hi + j;
            int ch = cq * 64 + l31;
            int idx = (b * 4096 + row) * 256 + ch;
            out[idx]      = x[idx]      + gam * (o0[4 * qq + j] * ri[j]);
            out[idx + 32] = x[idx + 32] + gam * (o1[4 * qq + j] * ri[j]);
        }
    }
}

// ---------------- launch ------------------------------------------------
extern "C" void kernel_launch(void* const* d_in, const int* in_sizes, int n_in,
                              void* d_out, int out_size, void* d_ws, size_t ws_size,
                              hipStream_t stream) {
    const float* x  = (const float*)d_in[0];
    const float* kf = (const float*)d_in[1];
    const float* kg = (const float*)d_in[2];
    const float* kh = (const float*)d_in[3];
    const float* gm = (const float*)d_in[4];
    float* out = (float*)d_out;

    char* ws = (char*)d_ws;
    unsigned short* wt = (unsigned short*)(ws);             // 320*256*2   = 163840 B
    unsigned short* fb = (unsigned short*)(ws + 163840);    // 16384*32*2  = 1 MiB
    unsigned short* gb = (unsigned short*)(ws + 1212416);   // 16384*32*2  = 1 MiB
    unsigned short* hT = (unsigned short*)(ws + 2260992);   // 4*256*4096*2= 8 MiB

    hipLaunchKernelGGL(k_wt,   dim3(320), dim3(256), 0, stream, kf, kg, kh, wt);
    hipLaunchKernelGGL(k_proj, dim3(512), dim3(256), 0, stream, x, wt, fb, gb, hT);
    hipLaunchKernelGGL(k_attn, dim3(256), dim3(512), 0, stream, x, fb, gb, hT, gm, out);
}

// Round 5
// 194.759 us; speedup vs baseline: 1.6843x; 1.6843x over previous
//
#include <hip/hip_runtime.h>

typedef __attribute__((ext_vector_type(8))) short bf16x8;
typedef __attribute__((ext_vector_type(4))) float f32x4;
typedef __attribute__((ext_vector_type(16))) float f32x16;

__device__ __forceinline__ unsigned short f2bf(float f) {  // RNE
    union { float f; unsigned u; } v; v.f = f;
    return (unsigned short)((v.u + 0x7FFFu + ((v.u >> 16) & 1u)) >> 16);
}
// packed round-half-up (hot path; differs from RNE only at exact ties)
__device__ __forceinline__ unsigned f2bf2_fast(float a, float b) {
    union { float f; unsigned u; } va, vb; va.f = a; vb.f = b;
    return ((va.u + 0x8000u) >> 16) | ((vb.u + 0x8000u) & 0xFFFF0000u);
}

__device__ __forceinline__ void async16(unsigned short* lds, const unsigned short* gsrc) {
    __builtin_amdgcn_global_load_lds(
        (const __attribute__((address_space(1))) void*)gsrc,
        (__attribute__((address_space(3))) void*)lds, 16, 0, 0);
}

// ---------------- Kernel 0: weight transpose + bf16 cast ----------------
__global__ __launch_bounds__(256) void k_wt(const float* __restrict__ kf,
                                            const float* __restrict__ kg,
                                            const float* __restrict__ kh,
                                            unsigned short* __restrict__ wt) {
    int n = blockIdx.x, t = threadIdx.x;
    const float* src; int stride, col;
    if (n < 32)      { src = kf; stride = 32;  col = n; }
    else if (n < 64) { src = kg; stride = 32;  col = n - 32; }
    else             { src = kh; stride = 256; col = n - 64; }
    wt[n * 256 + t] = f2bf(src[t * stride + col]);
}

// ---------------- Kernel 1: fused projections (fg + h) ------------------
__global__ __launch_bounds__(256) void k_proj(const float* __restrict__ x,
                                              const unsigned short* __restrict__ wt,
                                              unsigned short* __restrict__ f,
                                              unsigned short* __restrict__ g,
                                              unsigned short* __restrict__ hT) {
    __shared__ unsigned short s0[64][136];
    __shared__ unsigned short s1[64][136];
    int t = threadIdx.x;
    int w = t >> 6, lane = t & 63, q = lane >> 4, n15 = lane & 15;

    if (blockIdx.x < 256) {
        int rb = blockIdx.x;
        f32x4 acc[4];
#pragma unroll
        for (int i = 0; i < 4; ++i) acc[i] = (f32x4){0.f, 0.f, 0.f, 0.f};
        for (int kh2 = 0; kh2 < 2; ++kh2) {
            __syncthreads();
#pragma unroll
            for (int i = 0; i < 8; ++i) {
                int lin = i * 256 + t, row = lin >> 5, c4 = lin & 31;
                float4 v = *(const float4*)&x[(rb * 64 + row) * 256 + kh2 * 128 + c4 * 4];
                ushort4 o; o.x = f2bf(v.x); o.y = f2bf(v.y); o.z = f2bf(v.z); o.w = f2bf(v.w);
                *(ushort4*)&s0[row][c4 * 4] = o;
            }
#pragma unroll
            for (int i = 0; i < 4; ++i) {
                int lin = i * 256 + t, row = lin >> 4, s = lin & 15;
                *(uint4*)&s1[row][s * 8] = *(const uint4*)&wt[row * 256 + kh2 * 128 + s * 8];
            }
            __syncthreads();
#pragma unroll
            for (int kk = 0; kk < 4; ++kk) {
                bf16x8 a = *(const bf16x8*)&s0[w * 16 + n15][kk * 32 + q * 8];
#pragma unroll
                for (int nt = 0; nt < 4; ++nt) {
                    bf16x8 bw = *(const bf16x8*)&s1[nt * 16 + n15][kk * 32 + q * 8];
                    acc[nt] = __builtin_amdgcn_mfma_f32_16x16x32_bf16(a, bw, acc[nt], 0, 0, 0);
                }
            }
        }
#pragma unroll
        for (int nt = 0; nt < 4; ++nt)
#pragma unroll
            for (int r = 0; r < 4; ++r) {
                int grow = rb * 64 + w * 16 + q * 4 + r;
                int col = nt * 16 + n15;
                unsigned short v = f2bf(acc[nt][r]);
                if (col < 32) f[grow * 32 + col] = v;
                else          g[grow * 32 + (col - 32)] = v;
            }
    } else {
        int rt = blockIdx.x - 256;
        int b = rt >> 6, nbase = (rt & 63) * 64;
        f32x4 acc[4][4];
#pragma unroll
        for (int c = 0; c < 4; ++c)
#pragma unroll
            for (int i = 0; i < 4; ++i) acc[c][i] = (f32x4){0.f, 0.f, 0.f, 0.f};
        for (int kh2 = 0; kh2 < 2; ++kh2) {
            __syncthreads();
#pragma unroll
            for (int i = 0; i < 8; ++i) {
                int lin = i * 256 + t, row = lin >> 5, c4 = lin & 31;
                float4 v = *(const float4*)&x[(rt * 64 + row) * 256 + kh2 * 128 + c4 * 4];
                ushort4 o; o.x = f2bf(v.x); o.y = f2bf(v.y); o.z = f2bf(v.z); o.w = f2bf(v.w);
                *(ushort4*)&s0[row][c4 * 4] = o;
            }
            for (int ct = 0; ct < 4; ++ct) {
                if (ct) __syncthreads();
#pragma unroll
                for (int i = 0; i < 4; ++i) {
                    int lin = i * 256 + t, row = lin >> 4, s = lin & 15;
                    *(uint4*)&s1[row][s * 8] =
                        *(const uint4*)&wt[(64 + ct * 64 + row) * 256 + kh2 * 128 + s * 8];
                }
                __syncthreads();
#pragma unroll
                for (int kk = 0; kk < 4; ++kk) {
                    bf16x8 a = *(const bf16x8*)&s1[w * 16 + n15][kk * 32 + q * 8];
#pragma unroll
                    for (int nt = 0; nt < 4; ++nt) {
                        bf16x8 bx = *(const bf16x8*)&s0[nt * 16 + n15][kk * 32 + q * 8];
                        acc[ct][nt] = __builtin_amdgcn_mfma_f32_16x16x32_bf16(a, bx, acc[ct][nt], 0, 0, 0);
                    }
                }
            }
        }
#pragma unroll
        for (int ct = 0; ct < 4; ++ct)
#pragma unroll
            for (int nt = 0; nt < 4; ++nt)
#pragma unroll
                for (int r = 0; r < 4; ++r) {
                    int ch = ct * 64 + w * 16 + q * 4 + r;
                    int nloc = nbase + nt * 16 + n15;
                    hT[b * 1048576 + ch * 4096 + nloc] = f2bf(acc[ct][nt][r]);
                }
    }
}

// ---------------- Kernel 2: fused flash attention + residual ------------
// 512 thr = 8 waves. NON-REDUNDANT softmax via wave specialization:
//   S-phase (waves 0-3): wave w owns Q-rows w*16..+16. S^T = G.F^T with
//     16x16x32 (K=32 in one step) -> lane owns one row x 16 keys; max/sum
//     = in-lane reduce + shfl(16)+shfl(32); 16 exps/lane, 1x total.
//     P packed bf16 -> 8KB LDS tile in PV-A layout (b64, XOR-swizzled).
//   PV-phase (all 8 waves): 32x32x16, wave w: rows (w&1)*32, ch (w>>1)*64.
// Two barriers/iter; prefetch(kt+1) issued after B2 so its vmcnt drain at
// the next B0 is covered by the whole PV phase.
__global__ __launch_bounds__(512, 2) void k_attn(const float* __restrict__ x,
                                                 const unsigned short* __restrict__ f,
                                                 const unsigned short* __restrict__ g,
                                                 const unsigned short* __restrict__ hT,
                                                 const float* __restrict__ gamma_p,
                                                 float* __restrict__ out) {
    __shared__ unsigned short gs[2][64][32];   // keys x 32 dims (swizzled)   8 KB
    __shared__ unsigned short hs[2][256][64];  // ch x 64 keys (swizzled)    64 KB
    __shared__ unsigned short pls[64][64];     // P: rows x keys (swizzled)   8 KB
    __shared__ float als[64];                  // per-row alpha
    __shared__ float lrec[64];                 // per-row 1/l (epilogue)
    int t = threadIdx.x, bx = blockIdx.x;
    int b = (bx >> 1) & 3;                     // XCD swizzle: one batch per XCD
    int qt = ((bx & 1) << 5) | (bx >> 3);
    int qbase = qt * 64;
    int w = t >> 6, l = t & 63;
    int hi = l >> 5, l31 = l & 31;             // 32x32 roles (PV)
    int q = l >> 4, n15 = l & 15;              // 16x16 roles (S)
    int r2 = w & 1, c2 = w >> 1;               // PV: row-block, ch-block
    const bool is_s = (w < 4);                 // S-wave: rows w*16..+16

    // F B-frag (S-waves): B[n=qrow n15][k=8q+j], K=32 single step
    bf16x8 aFB;
    if (is_s)
        aFB = *(const bf16x8*)&f[(b * 4096 + qbase + w * 16 + n15) * 32 + q * 8];

    // staging source pointers (swizzle baked into source address)
    const unsigned short* hsrc = hT + b * 1048576 + (w * 32 + (l >> 3)) * 4096
                               + ((l & 7) ^ (l >> 3)) * 8;
    const unsigned short* gsrc = g + (b * 4096 + w * 16 + (l >> 2)) * 32
                               + ((l & 3) ^ ((l >> 2) & 3)) * 8;   // waves 0-3 only

    f32x16 o0, o1;
#pragma unroll
    for (int i = 0; i < 16; ++i) { o0[i] = 0.f; o1[i] = 0.f; }
    float m_run = -1e30f, l_run = 0.f;
    const f32x4 zero4 = (f32x4){0.f, 0.f, 0.f, 0.f};

    // prefetch tile 0
#pragma unroll
    for (int j = 0; j < 4; ++j) async16(&hs[0][w * 32 + j * 8][0], hsrc + j * 8 * 4096);
    if (w < 4) async16(&gs[0][w * 16][0], gsrc);

    for (int kt = 0; kt < 64; ++kt) {
        int cur = kt & 1, nxt = cur ^ 1;
        __syncthreads();                       // B0: drains prefetch(kt); buf reuse

        const unsigned short* gcur = &gs[cur][0][0];
        const unsigned short* hcur = &hs[cur][0][0];

        if (is_s) {
            // ---- S^T = G.F^T : 4 key-16 tiles, one K=32 step each ----
            f32x4 sa[4];
#pragma unroll
            for (int nt = 0; nt < 4; ++nt) {
                bf16x8 aG = *(const bf16x8*)&gcur[(nt * 16 + n15) * 32
                                                  + (q ^ (n15 & 3)) * 8];
                sa[nt] = __builtin_amdgcn_mfma_f32_16x16x32_bf16(aG, aFB, zero4, 0, 0, 0);
            }
            // row-max over lane's 16 keys + cross-q reduce (lane = q*16+n15)
            float mx = sa[0][0];
#pragma unroll
            for (int nt = 0; nt < 4; ++nt)
#pragma unroll
                for (int r = 0; r < 4; ++r) mx = fmaxf(mx, sa[nt][r]);
            mx = fmaxf(mx, __shfl_xor(mx, 16));
            mx = fmaxf(mx, __shfl_xor(mx, 32));
            float mnew = fmaxf(m_run, mx);
            float alpha = __expf(m_run - mnew);
            float ps = 0.f;
#pragma unroll
            for (int nt = 0; nt < 4; ++nt)
#pragma unroll
                for (int r = 0; r < 4; ++r) {
                    sa[nt][r] = __expf(sa[nt][r] - mnew);
                    ps += sa[nt][r];
                }
            ps += __shfl_xor(ps, 16);
            ps += __shfl_xor(ps, 32);
            l_run = l_run * alpha + ps;
            m_run = mnew;
            if (q == 0) als[w * 16 + n15] = alpha;
            // pack & write P: lane's key-quad kq = 4*nt+q, row = w*16+n15
            // phys addr = row*128B + ((kq>>1)^(row&7))*16B + (kq&1)*8B
#pragma unroll
            for (int nt = 0; nt < 4; ++nt) {
                unsigned p0 = f2bf2_fast(sa[nt][0], sa[nt][1]);
                unsigned p1 = f2bf2_fast(sa[nt][2], sa[nt][3]);
                int kq = 4 * nt + q;
                unsigned* dst = (unsigned*)&pls[w * 16 + n15][0]
                              + ((kq >> 1) ^ (n15 & 7)) * 4 + (kq & 1) * 2;
                dst[0] = p0; dst[1] = p1;
            }
        }
        __syncthreads();                       // B2: P/alpha visible

        if (kt + 1 < 64) {                     // prefetch flies over PV phase
            const unsigned short* hp = hsrc + (kt + 1) * 64;
#pragma unroll
            for (int j = 0; j < 4; ++j)
                async16(&hs[nxt][w * 32 + j * 8][0], hp + j * 8 * 4096);
            if (w < 4) async16(&gs[nxt][w * 16][0], gsrc + (kt + 1) * 2048);
        }

        // ---- rescale O by alpha (rows r2*32 + 8qq + 4hi + j) ----
#pragma unroll
        for (int qq = 0; qq < 4; ++qq) {
            f32x4 al = *(const f32x4*)&als[r2 * 32 + 8 * qq + 4 * hi];
#pragma unroll
            for (int j = 0; j < 4; ++j) {
                o0[4 * qq + j] *= al[j];
                o1[4 * qq + j] *= al[j];
            }
        }

        // ---- O += P.H : 32x32x16, 4 key-steps x 2 ch-tiles ----
#pragma unroll
        for (int ks = 0; ks < 4; ++ks) {
            int seg = ((2 * ks + hi) ^ (l31 & 7)) * 8;
            bf16x8 aP  = *(const bf16x8*)&pls[r2 * 32 + l31][seg];
            bf16x8 bH0 = *(const bf16x8*)&hcur[(c2 * 64 + l31) * 64 + seg];
            bf16x8 bH1 = *(const bf16x8*)&hcur[(c2 * 64 + 32 + l31) * 64 + seg];
            o0 = __builtin_amdgcn_mfma_f32_32x32x16_bf16(aP, bH0, o0, 0, 0, 0);
            o1 = __builtin_amdgcn_mfma_f32_32x32x16_bf16(aP, bH1, o1, 0, 0, 0);
        }
    }

    // ---- epilogue: O/l, residual, store ----
    if (is_s && q == 0) lrec[w * 16 + n15] = 1.0f / l_run;
    __syncthreads();
    float gam = *gamma_p;
#pragma unroll
    for (int qq = 0; qq < 4; ++qq) {
        f32x4 ri = *(const f32x4*)&lrec[r2 * 32 + 8 * qq + 4 * hi];
#pragma unroll
        for (int j = 0; j < 4; ++j) {
            int row = qbase + r2 * 32 + 8 * qq + 4 * hi + j;
            int ch = c2 * 64 + l31;
            int idx = (b * 4096 + row) * 256 + ch;
            out[idx]      = x[idx]      + gam * (o0[4 * qq + j] * ri[j]);
            out[idx + 32] = x[idx + 32] + gam * (o1[4 * qq + j] * ri[j]);
        }
    }
}

// ---------------- launch ------------------------------------------------
extern "C" void kernel_launch(void* const* d_in, const int* in_sizes, int n_in,
                              void* d_out, int out_size, void* d_ws, size_t ws_size,
                              hipStream_t stream) {
    const float* x  = (const float*)d_in[0];
    const float* kf = (const float*)d_in[1];
    const float* kg = (const float*)d_in[2];
    const float* kh = (const float*)d_in[3];
    const float* gm = (const float*)d_in[4];
    float* out = (float*)d_out;

    char* ws = (char*)d_ws;
    unsigned short* wt = (unsigned short*)(ws);             // 320*256*2   = 163840 B
    unsigned short* fb = (unsigned short*)(ws + 163840);    // 16384*32*2  = 1 MiB
    unsigned short* gb = (unsigned short*)(ws + 1212416);   // 16384*32*2  = 1 MiB
    unsigned short* hT = (unsigned short*)(ws + 2260992);   // 4*256*4096*2= 8 MiB

    hipLaunchKernelGGL(k_wt,   dim3(320), dim3(256), 0, stream, kf, kg, kh, wt);
    hipLaunchKernelGGL(k_proj, dim3(512), dim3(256), 0, stream, x, wt, fb, gb, hT);
    hipLaunchKernelGGL(k_attn, dim3(256), dim3(512), 0, stream, x, fb, gb, hT, gm, out);
}

// Round 7
// 177.013 us; speedup vs baseline: 1.8532x; 1.1002x over previous
//
#include <hip/hip_runtime.h>

typedef __attribute__((ext_vector_type(8))) short bf16x8;
typedef __attribute__((ext_vector_type(4))) float f32x4;
typedef __attribute__((ext_vector_type(16))) float f32x16;

__device__ __forceinline__ unsigned short f2bf(float f) {  // RNE
    union { float f; unsigned u; } v; v.f = f;
    return (unsigned short)((v.u + 0x7FFFu + ((v.u >> 16) & 1u)) >> 16);
}
// packed round-half-up (hot path; differs from RNE only at exact ties)
__device__ __forceinline__ unsigned f2bf2_fast(float a, float b) {
    union { float f; unsigned u; } va, vb; va.f = a; vb.f = b;
    return ((va.u + 0x8000u) >> 16) | ((vb.u + 0x8000u) & 0xFFFF0000u);
}

__device__ __forceinline__ void async16(unsigned short* lds, const unsigned short* gsrc) {
    __builtin_amdgcn_global_load_lds(
        (const __attribute__((address_space(1))) void*)gsrc,
        (__attribute__((address_space(3))) void*)lds, 16, 0, 0);
}

// ---------------- Kernel 0: weight transpose + bf16 cast (swizzled) ------
// wt row n (out-channel), 256 k-entries. 16B-chunk c stored at phys chunk
// c^(n&7) so tile staging is a flat memcpy and ds_read_b128 is conflict-free.
__global__ __launch_bounds__(256) void k_wt(const float* __restrict__ kf,
                                            const float* __restrict__ kg,
                                            const float* __restrict__ kh,
                                            unsigned short* __restrict__ wt) {
    int n = blockIdx.x, t = threadIdx.x;
    const float* src; int stride, col;
    if (n < 32)      { src = kf; stride = 32;  col = n; }
    else if (n < 64) { src = kg; stride = 32;  col = n - 32; }
    else             { src = kh; stride = 256; col = n - 64; }
    wt[n * 256 + (((t >> 3) ^ (n & 7)) << 3) + (t & 7)] = f2bf(src[t * stride + col]);
}

// ---------------- Kernel 1: projections, one WG = 64 rows x 320 cols -----
// 512 thr / 8 waves. x tile converted to LDS once (swizzled); W tiles
// double-buffered via global_load_lds (pre-swizzled layout -> flat memcpy).
// ct=0: f,g (D[row][col]); ct=1..4: hT (swapped operands, D[ch][row]).
__global__ __launch_bounds__(512) void k_proj(const float* __restrict__ x,
                                              const unsigned short* __restrict__ wt,
                                              unsigned short* __restrict__ f,
                                              unsigned short* __restrict__ g,
                                              unsigned short* __restrict__ hT) {
    __shared__ unsigned short xs[16384];      // 64 x 256 bf16, swizzled  32 KB
    __shared__ unsigned short ws[2][16384];   // W tile dbuf              64 KB
    int t = threadIdx.x, rb = blockIdx.x;
    int w = t >> 6, lane = t & 63, q = lane >> 4, n15 = lane & 15;
    int b = rb >> 6, nbase = (rb & 63) * 64;

    // x tile: 64 rows x 64 float4 = 4096 float4; row = lin>>6, c4 = lin&63.
    // (R6 crash: lin>>5/&31 ran row to 127 -> OOB global read. Fixed.)
#pragma unroll
    for (int i = 0; i < 8; ++i) {
        int lin = i * 512 + t, row = lin >> 6, c4 = lin & 63;
        float4 v = *(const float4*)&x[(rb * 64 + row) * 256 + c4 * 4];
        ushort4 o; o.x = f2bf(v.x); o.y = f2bf(v.y); o.z = f2bf(v.z); o.w = f2bf(v.w);
        *(ushort4*)&xs[row * 256 + (((c4 >> 1) ^ (row & 7)) << 3) + ((c4 & 1) << 2)] = o;
    }
    // W tile 0 async (flat 32 KB memcpy; layout pre-swizzled by k_wt)
#pragma unroll
    for (int j = 0; j < 4; ++j)
        async16(&ws[0][(j * 512 + w * 64) * 8], wt + (j * 512 + t) * 8);

    for (int ct = 0; ct < 5; ++ct) {
        int cur = ct & 1, nxt = cur ^ 1;
        __syncthreads();                       // drains W(ct) (+x writes at ct=0)
        if (ct < 4) {
            const unsigned short* wsrc = wt + (ct + 1) * 16384;
#pragma unroll
            for (int j = 0; j < 4; ++j)
                async16(&ws[nxt][(j * 512 + w * 64) * 8], wsrc + (j * 512 + t) * 8);
        }
        const unsigned short* wcur = ws[cur];
        f32x4 acc[2];
        acc[0] = (f32x4){0.f, 0.f, 0.f, 0.f};
        acc[1] = (f32x4){0.f, 0.f, 0.f, 0.f};

        if (ct == 0) {                         // f,g : D[m=row][n=col]
            int rg = w & 3, cg = w >> 2;
#pragma unroll
            for (int kk = 0; kk < 8; ++kk) {
                bf16x8 a = *(const bf16x8*)&xs[(rg * 16 + n15) * 256
                                + ((((kk << 2) + q) ^ (n15 & 7)) << 3)];
#pragma unroll
                for (int nt = 0; nt < 2; ++nt) {
                    bf16x8 bw = *(const bf16x8*)&wcur[(cg * 32 + nt * 16 + n15) * 256
                                    + ((((kk << 2) + q) ^ (n15 & 7)) << 3)];
                    acc[nt] = __builtin_amdgcn_mfma_f32_16x16x32_bf16(a, bw, acc[nt], 0, 0, 0);
                }
            }
#pragma unroll
            for (int nt = 0; nt < 2; ++nt)
#pragma unroll
                for (int r = 0; r < 4; ++r) {
                    int grow = rb * 64 + rg * 16 + q * 4 + r;
                    int col = cg * 32 + nt * 16 + n15;
                    unsigned short v = f2bf(acc[nt][r]);
                    if (col < 32) f[grow * 32 + col] = v;
                    else          g[grow * 32 + (col - 32)] = v;
                }
        } else {                               // h : D[m=ch][n=row] (swapped)
            int cg = w & 3, rg = w >> 2;
#pragma unroll
            for (int kk = 0; kk < 8; ++kk) {
                bf16x8 a = *(const bf16x8*)&wcur[(cg * 16 + n15) * 256
                                + ((((kk << 2) + q) ^ (n15 & 7)) << 3)];
#pragma unroll
                for (int nt = 0; nt < 2; ++nt) {
                    bf16x8 bx = *(const bf16x8*)&xs[(rg * 32 + nt * 16 + n15) * 256
                                    + ((((kk << 2) + q) ^ (n15 & 7)) << 3)];
                    acc[nt] = __builtin_amdgcn_mfma_f32_16x16x32_bf16(a, bx, acc[nt], 0, 0, 0);
                }
            }
#pragma unroll
            for (int nt = 0; nt < 2; ++nt)
#pragma unroll
                for (int r = 0; r < 4; ++r) {
                    int ch = (ct - 1) * 64 + cg * 16 + q * 4 + r;
                    int nloc = nbase + rg * 32 + nt * 16 + n15;
                    hT[b * 1048576 + ch * 4096 + nloc] = f2bf(acc[nt][r]);
                }
        }
    }
}

// ---------------- Kernel 2: fused flash attention + residual -------------
// 1024 thr / 16 waves (4 waves/SIMD for latency hiding).
//   S-phase (waves 0-3): wave w owns Q-rows w*16..+16; G frags live in
//     REGISTERS (global-prefetched one iter ahead) -> no gs LDS at all.
//     16 exps/lane, computed once; P -> 8 KB LDS tile in PV-A layout.
//   PV-phase (all 16 waves): 32x32x16; wave = (row-block w&1) x (ch-block w>>1).
// Two barriers/iter; hs prefetch issued after B2, drained at next B0.
__global__ __launch_bounds__(1024, 4) void k_attn(const float* __restrict__ x,
                                                  const unsigned short* __restrict__ f,
                                                  const unsigned short* __restrict__ g,
                                                  const unsigned short* __restrict__ hT,
                                                  const float* __restrict__ gamma_p,
                                                  float* __restrict__ out) {
    __shared__ unsigned short hs[2][16384];    // 256 ch x 64 keys, swizzled 64 KB
    __shared__ unsigned short pls[4096];       // P: 64 rows x 64 keys       8 KB
    __shared__ float als[64];                  // per-row alpha
    __shared__ float lrec[64];                 // per-row 1/l
    int t = threadIdx.x, bx = blockIdx.x;
    int b = (bx >> 1) & 3;                     // XCD swizzle: one batch per XCD
    int qt = ((bx & 1) << 5) | (bx >> 3);
    int qbase = qt * 64;
    int w = t >> 6, l = t & 63;
    int hi = l >> 5, l31 = l & 31;             // 32x32 roles (PV)
    int q = l >> 4, n15 = l & 15;              // 16x16 roles (S)
    int rw = w & 1, cw = w >> 1;               // PV: row-block(32) x ch-block(32)
    const bool is_s = (w < 4);

    // F B-frag (S-waves): B[n=qrow n15][k=8q+j], K=32 single step
    bf16x8 aFB;
    if (is_s)
        aFB = *(const bf16x8*)&f[(b * 4096 + qbase + w * 16 + n15) * 32 + q * 8];

    // hs staging: thread t covers 16B-chunks t and t+1024 of the 2048-chunk
    // tile. chunk c: ch=c>>3, phys seg c&7 holds logical seg (c&7)^(ch&7).
    const unsigned short* hsrc = hT + b * 1048576 + (t >> 3) * 4096
                               + (((t & 7) ^ ((t >> 3) & 7)) << 3);

    // G A-frags in registers, prefetched one iter ahead
    const unsigned short* gbase = g + (b * 4096 + n15) * 32 + q * 8;
    bf16x8 aG[4], aGn[4];
    if (is_s) {
#pragma unroll
        for (int nt = 0; nt < 4; ++nt)
            aG[nt] = *(const bf16x8*)&gbase[(nt * 16) * 32];
    }

    f32x16 o;
#pragma unroll
    for (int i = 0; i < 16; ++i) o[i] = 0.f;
    float m_run = -1e30f, l_run = 0.f;
    const f32x4 zero4 = (f32x4){0.f, 0.f, 0.f, 0.f};

    // prefetch hs tile 0
    async16(&hs[0][w * 512], hsrc);
    async16(&hs[0][8192 + w * 512], hsrc + 128 * 4096);

    for (int kt = 0; kt < 64; ++kt) {
        int cur = kt & 1, nxt = cur ^ 1;
        __syncthreads();                       // B0: drains hs(kt) + aGn loads

        if (is_s) {
            // ---- S^T = G.F^T : 4 key-16 tiles, one K=32 step each ----
            f32x4 sa[4];
#pragma unroll
            for (int nt = 0; nt < 4; ++nt)
                sa[nt] = __builtin_amdgcn_mfma_f32_16x16x32_bf16(aG[nt], aFB, zero4, 0, 0, 0);
            // prefetch G for kt+1 (in flight through PV + next B0)
            int ktn = (kt + 1) & 63;
#pragma unroll
            for (int nt = 0; nt < 4; ++nt)
                aGn[nt] = *(const bf16x8*)&gbase[(ktn * 64 + nt * 16) * 32];
            // row-max over lane's 16 keys + cross-q reduce
            float mx = sa[0][0];
#pragma unroll
            for (int nt = 0; nt < 4; ++nt)
#pragma unroll
                for (int r = 0; r < 4; ++r) mx = fmaxf(mx, sa[nt][r]);
            mx = fmaxf(mx, __shfl_xor(mx, 16));
            mx = fmaxf(mx, __shfl_xor(mx, 32));
            float mnew = fmaxf(m_run, mx);
            float alpha = __expf(m_run - mnew);
            float ps = 0.f;
#pragma unroll
            for (int nt = 0; nt < 4; ++nt)
#pragma unroll
                for (int r = 0; r < 4; ++r) {
                    sa[nt][r] = __expf(sa[nt][r] - mnew);
                    ps += sa[nt][r];
                }
            ps += __shfl_xor(ps, 16);
            ps += __shfl_xor(ps, 32);
            l_run = l_run * alpha + ps;
            m_run = mnew;
            if (q == 0) als[w * 16 + n15] = alpha;
            // pack & write P: key-quad kq=4nt+q, row=w*16+n15
            // phys = row*128B + ((kq>>1)^(row&7))*16B + (kq&1)*8B
#pragma unroll
            for (int nt = 0; nt < 4; ++nt) {
                unsigned p0 = f2bf2_fast(sa[nt][0], sa[nt][1]);
                unsigned p1 = f2bf2_fast(sa[nt][2], sa[nt][3]);
                int kq = 4 * nt + q;
                unsigned* dst = (unsigned*)&pls[(w * 16 + n15) * 64]
                              + ((kq >> 1) ^ (n15 & 7)) * 4 + (kq & 1) * 2;
                dst[0] = p0; dst[1] = p1;
            }
#pragma unroll
            for (int nt = 0; nt < 4; ++nt) aG[nt] = aGn[nt];
        }
        __syncthreads();                       // B2: P/alpha visible

        if (kt + 1 < 64) {                     // hs prefetch flies over PV
            const unsigned short* hp = hsrc + (kt + 1) * 64;
            async16(&hs[nxt][w * 512], hp);
            async16(&hs[nxt][8192 + w * 512], hp + 128 * 4096);
        }

        // ---- rescale O by alpha (rows rw*32 + 8qq + 4hi + j) ----
#pragma unroll
        for (int qq = 0; qq < 4; ++qq) {
            f32x4 al = *(const f32x4*)&als[rw * 32 + 8 * qq + 4 * hi];
#pragma unroll
            for (int j = 0; j < 4; ++j) o[4 * qq + j] *= al[j];
        }

        // ---- O += P.H : 32x32x16, 4 key-steps, one 32-ch tile ----
        const unsigned short* hcur = &hs[cur][0];
#pragma unroll
        for (int ks = 0; ks < 4; ++ks) {
            int seg = (((2 * ks + hi) ^ (l31 & 7)) << 3);
            bf16x8 aP = *(const bf16x8*)&pls[(rw * 32 + l31) * 64 + seg];
            bf16x8 bH = *(const bf16x8*)&hcur[(cw * 32 + l31) * 64 + seg];
            o = __builtin_amdgcn_mfma_f32_32x32x16_bf16(aP, bH, o, 0, 0, 0);
        }
    }

    // ---- epilogue: O/l, residual, store ----
    if (is_s && q == 0) lrec[w * 16 + n15] = 1.0f / l_run;
    __syncthreads();
    float gam = *gamma_p;
#pragma unroll
    for (int qq = 0; qq < 4; ++qq) {
        f32x4 ri = *(const f32x4*)&lrec[rw * 32 + 8 * qq + 4 * hi];
#pragma unroll
        for (int j = 0; j < 4; ++j) {
            int row = qbase + rw * 32 + 8 * qq + 4 * hi + j;
            int ch = cw * 32 + l31;
            int idx = (b * 4096 + row) * 256 + ch;
            out[idx] = x[idx] + gam * (o[4 * qq + j] * ri[j]);
        }
    }
}

// ---------------- launch ------------------------------------------------
extern "C" void kernel_launch(void* const* d_in, const int* in_sizes, int n_in,
                              void* d_out, int out_size, void* d_ws, size_t ws_size,
                              hipStream_t stream) {
    const float* x  = (const float*)d_in[0];
    const float* kf = (const float*)d_in[1];
    const float* kg = (const float*)d_in[2];
    const float* kh = (const float*)d_in[3];
    const float* gm = (const float*)d_in[4];
    float* out = (float*)d_out;

    char* ws = (char*)d_ws;
    unsigned short* wt = (unsigned short*)(ws);             // 320*256*2   = 163840 B
    unsigned short* fb = (unsigned short*)(ws + 163840);    // 16384*32*2  = 1 MiB
    unsigned short* gb = (unsigned short*)(ws + 1212416);   // 16384*32*2  = 1 MiB
    unsigned short* hT = (unsigned short*)(ws + 2260992);   // 4*256*4096*2= 8 MiB

    hipLaunchKernelGGL(k_wt,   dim3(320), dim3(256),  0, stream, kf, kg, kh, wt);
    hipLaunchKernelGGL(k_proj, dim3(256), dim3(512),  0, stream, x, wt, fb, gb, hT);
    hipLaunchKernelGGL(k_attn, dim3(256), dim3(1024), 0, stream, x, fb, gb, hT, gm, out);
}

// Round 8
// 165.820 us; speedup vs baseline: 1.9783x; 1.0675x over previous
//
#include <hip/hip_runtime.h>

typedef __attribute__((ext_vector_type(8))) short bf16x8;
typedef __attribute__((ext_vector_type(4))) float f32x4;
typedef __attribute__((ext_vector_type(16))) float f32x16;

__device__ __forceinline__ unsigned short f2bf(float f) {  // RNE
    union { float f; unsigned u; } v; v.f = f;
    return (unsigned short)((v.u + 0x7FFFu + ((v.u >> 16) & 1u)) >> 16);
}
// packed round-half-up (hot path; differs from RNE only at exact ties)
__device__ __forceinline__ unsigned f2bf2_fast(float a, float b) {
    union { float f; unsigned u; } va, vb; va.f = a; vb.f = b;
    return ((va.u + 0x8000u) >> 16) | ((vb.u + 0x8000u) & 0xFFFF0000u);
}

__device__ __forceinline__ void async16(unsigned short* lds, const unsigned short* gsrc) {
    __builtin_amdgcn_global_load_lds(
        (const __attribute__((address_space(1))) void*)gsrc,
        (__attribute__((address_space(3))) void*)lds, 16, 0, 0);
}

// ---------------- Kernel 0: weight transpose + bf16 cast (swizzled) ------
// wt row n (out-channel), 256 k-entries. 16B-chunk c stored at phys chunk
// c^(n&7) so tile staging is a flat memcpy and ds_read_b128 is conflict-free.
__global__ __launch_bounds__(256) void k_wt(const float* __restrict__ kf,
                                            const float* __restrict__ kg,
                                            const float* __restrict__ kh,
                                            unsigned short* __restrict__ wt) {
    int n = blockIdx.x, t = threadIdx.x;
    const float* src; int stride, col;
    if (n < 32)      { src = kf; stride = 32;  col = n; }
    else if (n < 64) { src = kg; stride = 32;  col = n - 32; }
    else             { src = kh; stride = 256; col = n - 64; }
    wt[n * 256 + (((t >> 3) ^ (n & 7)) << 3) + (t & 7)] = f2bf(src[t * stride + col]);
}

// ---------------- Kernel 1: projections, one WG = 64 rows x 320 cols -----
// (unchanged from round 7 — works, and evidence says non-attn time is
// dominated by fixed overhead, not this kernel)
__global__ __launch_bounds__(512) void k_proj(const float* __restrict__ x,
                                              const unsigned short* __restrict__ wt,
                                              unsigned short* __restrict__ f,
                                              unsigned short* __restrict__ g,
                                              unsigned short* __restrict__ hT) {
    __shared__ unsigned short xs[16384];      // 64 x 256 bf16, swizzled  32 KB
    __shared__ unsigned short ws[2][16384];   // W tile dbuf              64 KB
    int t = threadIdx.x, rb = blockIdx.x;
    int w = t >> 6, lane = t & 63, q = lane >> 4, n15 = lane & 15;
    int b = rb >> 6, nbase = (rb & 63) * 64;

#pragma unroll
    for (int i = 0; i < 8; ++i) {
        int lin = i * 512 + t, row = lin >> 6, c4 = lin & 63;
        float4 v = *(const float4*)&x[(rb * 64 + row) * 256 + c4 * 4];
        ushort4 o; o.x = f2bf(v.x); o.y = f2bf(v.y); o.z = f2bf(v.z); o.w = f2bf(v.w);
        *(ushort4*)&xs[row * 256 + (((c4 >> 1) ^ (row & 7)) << 3) + ((c4 & 1) << 2)] = o;
    }
#pragma unroll
    for (int j = 0; j < 4; ++j)
        async16(&ws[0][(j * 512 + w * 64) * 8], wt + (j * 512 + t) * 8);

    for (int ct = 0; ct < 5; ++ct) {
        int cur = ct & 1, nxt = cur ^ 1;
        __syncthreads();
        if (ct < 4) {
            const unsigned short* wsrc = wt + (ct + 1) * 16384;
#pragma unroll
            for (int j = 0; j < 4; ++j)
                async16(&ws[nxt][(j * 512 + w * 64) * 8], wsrc + (j * 512 + t) * 8);
        }
        const unsigned short* wcur = ws[cur];
        f32x4 acc[2];
        acc[0] = (f32x4){0.f, 0.f, 0.f, 0.f};
        acc[1] = (f32x4){0.f, 0.f, 0.f, 0.f};

        if (ct == 0) {                         // f,g : D[m=row][n=col]
            int rg = w & 3, cg = w >> 2;
#pragma unroll
            for (int kk = 0; kk < 8; ++kk) {
                bf16x8 a = *(const bf16x8*)&xs[(rg * 16 + n15) * 256
                                + ((((kk << 2) + q) ^ (n15 & 7)) << 3)];
#pragma unroll
                for (int nt = 0; nt < 2; ++nt) {
                    bf16x8 bw = *(const bf16x8*)&wcur[(cg * 32 + nt * 16 + n15) * 256
                                    + ((((kk << 2) + q) ^ (n15 & 7)) << 3)];
                    acc[nt] = __builtin_amdgcn_mfma_f32_16x16x32_bf16(a, bw, acc[nt], 0, 0, 0);
                }
            }
#pragma unroll
            for (int nt = 0; nt < 2; ++nt)
#pragma unroll
                for (int r = 0; r < 4; ++r) {
                    int grow = rb * 64 + rg * 16 + q * 4 + r;
                    int col = cg * 32 + nt * 16 + n15;
                    unsigned short v = f2bf(acc[nt][r]);
                    if (col < 32) f[grow * 32 + col] = v;
                    else          g[grow * 32 + (col - 32)] = v;
                }
        } else {                               // h : D[m=ch][n=row] (swapped)
            int cg = w & 3, rg = w >> 2;
#pragma unroll
            for (int kk = 0; kk < 8; ++kk) {
                bf16x8 a = *(const bf16x8*)&wcur[(cg * 16 + n15) * 256
                                + ((((kk << 2) + q) ^ (n15 & 7)) << 3)];
#pragma unroll
                for (int nt = 0; nt < 2; ++nt) {
                    bf16x8 bx = *(const bf16x8*)&xs[(rg * 32 + nt * 16 + n15) * 256
                                    + ((((kk << 2) + q) ^ (n15 & 7)) << 3)];
                    acc[nt] = __builtin_amdgcn_mfma_f32_16x16x32_bf16(a, bx, acc[nt], 0, 0, 0);
                }
            }
#pragma unroll
            for (int nt = 0; nt < 2; ++nt)
#pragma unroll
                for (int r = 0; r < 4; ++r) {
                    int ch = (ct - 1) * 64 + cg * 16 + q * 4 + r;
                    int nloc = nbase + rg * 32 + nt * 16 + n15;
                    hT[b * 1048576 + ch * 4096 + nloc] = f2bf(acc[nt][r]);
                }
        }
    }
}

// ---------------- Kernel 2: fused flash attention + residual -------------
// 1024 thr / 16 waves. PIPELINED producer/consumer, ONE barrier/iter:
//   phase kt: S-waves (w<4, one per SIMD) compute S(kt+1)->pls[nxt]/als[nxt]
//   while ALL waves run rescale+PV(kt) from pls[cur]/hs[cur]. End-barrier
//   publishes pls[nxt]/als[nxt] and drains the hs[nxt] DMA.
// Tile j lives in buffer j&1 for pls/als/hs. G frags in registers,
// prefetched one tile ahead. alpha(0)=exp(-1e30-m0)=0 makes prologue exact.
__global__ __launch_bounds__(1024, 4) void k_attn(const float* __restrict__ x,
                                                  const unsigned short* __restrict__ f,
                                                  const unsigned short* __restrict__ g,
                                                  const unsigned short* __restrict__ hT,
                                                  const float* __restrict__ gamma_p,
                                                  float* __restrict__ out) {
    __shared__ unsigned short hs[2][16384];    // 256 ch x 64 keys, swizzled 64 KB
    __shared__ unsigned short pls[2][4096];    // P dbuf: 64 rows x 64 keys  16 KB
    __shared__ float als[2][64];               // per-row alpha dbuf
    __shared__ float lrec[64];                 // per-row 1/l
    int t = threadIdx.x, bx = blockIdx.x;
    int b = (bx >> 1) & 3;                     // XCD-pair per batch
    int qt = ((bx & 1) << 5) | (bx >> 3);
    int qbase = qt * 64;
    int w = t >> 6, l = t & 63;
    int hi = l >> 5, l31 = l & 31;             // 32x32 roles (PV)
    int q = l >> 4, n15 = l & 15;              // 16x16 roles (S)
    int rw = w & 1, cw = w >> 1;               // PV: row-block(32) x ch-block(32)
    const bool is_s = (w < 4);

    // F B-frag (S-waves): B[n=qrow n15][k=8q+j], K=32 single step
    bf16x8 aFB;
    if (is_s)
        aFB = *(const bf16x8*)&f[(b * 4096 + qbase + w * 16 + n15) * 32 + q * 8];

    // hs staging: thread t covers 16B-chunks t and t+1024 of the 2048-chunk
    // tile. chunk c: ch=c>>3, phys seg c&7 holds logical seg (c&7)^(ch&7).
    const unsigned short* hsrc = hT + b * 1048576 + (t >> 3) * 4096
                               + (((t & 7) ^ ((t >> 3) & 7)) << 3);

    const unsigned short* gbase = g + (b * 4096 + n15) * 32 + q * 8;
    bf16x8 aG[4], aGn[4];

    f32x16 o;
#pragma unroll
    for (int i = 0; i < 16; ++i) o[i] = 0.f;
    float m_run = -1e30f, l_run = 0.f;
    const f32x4 zero4 = (f32x4){0.f, 0.f, 0.f, 0.f};

    // S-step for the tile currently in aG, writing buffer `buf`
    auto s_tile = [&](int buf) {
        f32x4 sa[4];
#pragma unroll
        for (int nt = 0; nt < 4; ++nt)
            sa[nt] = __builtin_amdgcn_mfma_f32_16x16x32_bf16(aG[nt], aFB, zero4, 0, 0, 0);
        float mx = sa[0][0];
#pragma unroll
        for (int nt = 0; nt < 4; ++nt)
#pragma unroll
            for (int r = 0; r < 4; ++r) mx = fmaxf(mx, sa[nt][r]);
        mx = fmaxf(mx, __shfl_xor(mx, 16));
        mx = fmaxf(mx, __shfl_xor(mx, 32));
        float mnew = fmaxf(m_run, mx);
        float alpha = __expf(m_run - mnew);
        float ps = 0.f;
#pragma unroll
        for (int nt = 0; nt < 4; ++nt)
#pragma unroll
            for (int r = 0; r < 4; ++r) {
                sa[nt][r] = __expf(sa[nt][r] - mnew);
                ps += sa[nt][r];
            }
        ps += __shfl_xor(ps, 16);
        ps += __shfl_xor(ps, 32);
        l_run = l_run * alpha + ps;
        m_run = mnew;
        if (q == 0) als[buf][w * 16 + n15] = alpha;
        // pack & write P: key-quad kq=4nt+q, row=w*16+n15
        // phys = row*128B + ((kq>>1)^(row&7))*16B + (kq&1)*8B
#pragma unroll
        for (int nt = 0; nt < 4; ++nt) {
            unsigned p0 = f2bf2_fast(sa[nt][0], sa[nt][1]);
            unsigned p1 = f2bf2_fast(sa[nt][2], sa[nt][3]);
            int kq = 4 * nt + q;
            unsigned* dst = (unsigned*)&pls[buf][(w * 16 + n15) * 64]
                          + ((kq >> 1) ^ (n15 & 7)) * 4 + (kq & 1) * 2;
            dst[0] = p0; dst[1] = p1;
        }
    };

    // ---- prologue: hs(0) prefetch; S(0) -> pls[0]/als[0]; aG <- tile 1 ----
    async16(&hs[0][w * 512], hsrc);
    async16(&hs[0][8192 + w * 512], hsrc + 128 * 4096);
    if (is_s) {
#pragma unroll
        for (int nt = 0; nt < 4; ++nt)
            aG[nt] = *(const bf16x8*)&gbase[(nt * 16) * 32];
#pragma unroll
        for (int nt = 0; nt < 4; ++nt)
            aGn[nt] = *(const bf16x8*)&gbase[(64 + nt * 16) * 32];
        s_tile(0);
#pragma unroll
        for (int nt = 0; nt < 4; ++nt) aG[nt] = aGn[nt];
    }
    __syncthreads();   // publishes pls[0]/als[0]; drains hs[0]

    for (int kt = 0; kt < 64; ++kt) {
        int cur = kt & 1, nxt = cur ^ 1;

        if (kt + 1 < 64) {                     // hs(kt+1) flies over this phase
            const unsigned short* hp = hsrc + (kt + 1) * 64;
            async16(&hs[nxt][w * 512], hp);
            async16(&hs[nxt][8192 + w * 512], hp + 128 * 4096);
        }

        if (is_s && kt + 1 < 64) {
            // issue G loads for tile kt+2 first so they fly during s_tile
            int ktn = (kt + 2 < 64) ? kt + 2 : 63;
#pragma unroll
            for (int nt = 0; nt < 4; ++nt)
                aGn[nt] = *(const bf16x8*)&gbase[(ktn * 64 + nt * 16) * 32];
            s_tile(nxt);                       // S(kt+1) from aG (= tile kt+1)
#pragma unroll
            for (int nt = 0; nt < 4; ++nt) aG[nt] = aGn[nt];
        }

        // ---- rescale O by alpha(kt) ----
#pragma unroll
        for (int qq = 0; qq < 4; ++qq) {
            f32x4 al = *(const f32x4*)&als[cur][rw * 32 + 8 * qq + 4 * hi];
#pragma unroll
            for (int j = 0; j < 4; ++j) o[4 * qq + j] *= al[j];
        }

        // ---- O += P(kt).H(kt) : 32x32x16, 4 key-steps ----
        const unsigned short* hcur = &hs[cur][0];
        const unsigned short* pcur = &pls[cur][0];
#pragma unroll
        for (int ks = 0; ks < 4; ++ks) {
            int seg = (((2 * ks + hi) ^ (l31 & 7)) << 3);
            bf16x8 aP = *(const bf16x8*)&pcur[(rw * 32 + l31) * 64 + seg];
            bf16x8 bH = *(const bf16x8*)&hcur[(cw * 32 + l31) * 64 + seg];
            o = __builtin_amdgcn_mfma_f32_32x32x16_bf16(aP, bH, o, 0, 0, 0);
        }

        __syncthreads();   // publish pls[nxt]/als[nxt]; drain hs[nxt] DMA
    }

    // ---- epilogue: O/l, residual, store ----
    if (is_s && q == 0) lrec[w * 16 + n15] = 1.0f / l_run;
    __syncthreads();
    float gam = *gamma_p;
#pragma unroll
    for (int qq = 0; qq < 4; ++qq) {
        f32x4 ri = *(const f32x4*)&lrec[rw * 32 + 8 * qq + 4 * hi];
#pragma unroll
        for (int j = 0; j < 4; ++j) {
            int row = qbase + rw * 32 + 8 * qq + 4 * hi + j;
            int ch = cw * 32 + l31;
            int idx = (b * 4096 + row) * 256 + ch;
            out[idx] = x[idx] + gam * (o[4 * qq + j] * ri[j]);
        }
    }
}

// ---------------- launch ------------------------------------------------
extern "C" void kernel_launch(void* const* d_in, const int* in_sizes, int n_in,
                              void* d_out, int out_size, void* d_ws, size_t ws_size,
                              hipStream_t stream) {
    const float* x  = (const float*)d_in[0];
    const float* kf = (const float*)d_in[1];
    const float* kg = (const float*)d_in[2];
    const float* kh = (const float*)d_in[3];
    const float* gm = (const float*)d_in[4];
    float* out = (float*)d_out;

    char* ws = (char*)d_ws;
    unsigned short* wt = (unsigned short*)(ws);             // 320*256*2   = 163840 B
    unsigned short* fb = (unsigned short*)(ws + 163840);    // 16384*32*2  = 1 MiB
    unsigned short* gb = (unsigned short*)(ws + 1212416);   // 16384*32*2  = 1 MiB
    unsigned short* hT = (unsigned short*)(ws + 2260992);   // 4*256*4096*2= 8 MiB

    hipLaunchKernelGGL(k_wt,   dim3(320), dim3(256),  0, stream, kf, kg, kh, wt);
    hipLaunchKernelGGL(k_proj, dim3(256), dim3(512),  0, stream, x, wt, fb, gb, hT);
    hipLaunchKernelGGL(k_attn, dim3(256), dim3(1024), 0, stream, x, fb, gb, hT, gm, out);
}